// Round 1
// baseline (484.894 us; speedup 1.0000x reference)
//
#include <hip/hip_runtime.h>
#include <math.h>

#define N 512
#define LOGN 9

// (512 * 0.1)^2 -- mask boundary. Integer dist^2 values are exact in fp32 so
// comparing squared distances matches the reference's sqrt(dist) <= 51.2f.
__device__ __constant__ float kRadius2 = 51.2f * 51.2f;

// In-LDS 512-point radix-2 DIT FFT. Data must be loaded bit-reversed.
// Twiddle table: tw[k] = e^{-2*pi*i*k/512} stored as (cos, sin) with the
// multiply done as (c - i*s)*(xr + i*xi).
__device__ __forceinline__ void fft512(float* sRe, float* sIm,
                                       const float* twRe, const float* twIm,
                                       int t) {
#pragma unroll
    for (int s = 1; s <= LOGN; ++s) {
        __syncthreads();
        int half = 1 << (s - 1);
        int pos  = t & (half - 1);
        int i1   = ((t >> (s - 1)) << s) + pos;
        int i2   = i1 + half;
        int twi  = pos << (LOGN - s);
        float c  = twRe[twi];
        float sn = twIm[twi];
        float xr = sRe[i2], xi = sIm[i2];
        float tr = c * xr + sn * xi;   // (c - i*sn) * (xr + i*xi)
        float ti = c * xi - sn * xr;
        float ur = sRe[i1], ui = sIm[i1];
        sRe[i2] = ur - tr; sIm[i2] = ui - ti;
        sRe[i1] = ur + tr; sIm[i1] = ui + ti;
    }
    __syncthreads();
}

// Kernel 1: grayscale (mean over C=3) + row FFT. One block per (b, h) row.
__global__ __launch_bounds__(256) void k_gray_rowfft(
    const float* __restrict__ img, float2* __restrict__ buf) {
    __shared__ float sRe[N], sIm[N];
    __shared__ float twRe[N / 2], twIm[N / 2];

    const int t = threadIdx.x;
    const int h = blockIdx.x;
    const int b = blockIdx.y;

    float ang = (float)(2.0 * M_PI / (double)N) * (float)t;
    twRe[t] = cosf(ang);
    twIm[t] = sinf(ang);

    const size_t plane = (size_t)N * N;
    const float* base = img + (size_t)b * 3 * plane + (size_t)h * N;

#pragma unroll
    for (int k = 0; k < 2; ++k) {
        int w = t + k * 256;
        float g = (base[w] + base[plane + w] + base[2 * plane + w]) *
                  (1.0f / 3.0f);
        int r = __brev((unsigned)w) >> (32 - LOGN);
        sRe[r] = g;
        sIm[r] = 0.0f;
    }

    fft512(sRe, sIm, twRe, twIm, t);

    float2* out = buf + ((size_t)b * N + h) * N;
#pragma unroll
    for (int k = 0; k < 2; ++k) {
        int w = t + k * 256;
        out[w] = make_float2(sRe[w], sIm[w]);
    }
}

// Kernel 2: column FFT + masked/total magnitude reduction.
// One block per (b, w) column. acc[b*2] = masked sum, acc[b*2+1] = total sum.
__global__ __launch_bounds__(256) void k_colfft_reduce(
    const float2* __restrict__ buf, float* __restrict__ acc) {
    __shared__ float sRe[N], sIm[N];
    __shared__ float twRe[N / 2], twIm[N / 2];
    __shared__ float red[8];

    const int t = threadIdx.x;
    const int w = blockIdx.x;
    const int b = blockIdx.y;

    float ang = (float)(2.0 * M_PI / (double)N) * (float)t;
    twRe[t] = cosf(ang);
    twIm[t] = sinf(ang);

    const float2* col = buf + (size_t)b * N * N + w;
#pragma unroll
    for (int k = 0; k < 2; ++k) {
        int h = t + k * 256;
        float2 v = col[(size_t)h * N];
        int r = __brev((unsigned)h) >> (32 - LOGN);
        sRe[r] = v.x;
        sIm[r] = v.y;
    }

    fft512(sRe, sIm, twRe, twIm, t);

    float msum = 0.0f, tsum = 0.0f;
    float dx = (float)(w - 256);
    float dx2 = dx * dx;
#pragma unroll
    for (int k = 0; k < 2; ++k) {
        int hh = t + k * 256;
        float re = sRe[hh], im = sIm[hh];
        float mag = sqrtf(re * re + im * im);
        tsum += mag;
        float dy = (float)(hh - 256);
        if (dy * dy + dx2 <= kRadius2) msum += mag;
    }

    // 64-lane wave reduce, then cross-wave via LDS.
#pragma unroll
    for (int off = 32; off > 0; off >>= 1) {
        msum += __shfl_down(msum, off);
        tsum += __shfl_down(tsum, off);
    }
    int wave = t >> 6;
    int lane = t & 63;
    if (lane == 0) {
        red[wave * 2 + 0] = msum;
        red[wave * 2 + 1] = tsum;
    }
    __syncthreads();
    if (t == 0) {
        float m = red[0] + red[2] + red[4] + red[6];
        float s = red[1] + red[3] + red[5] + red[7];
        atomicAdd(&acc[b * 2 + 0], m);
        atomicAdd(&acc[b * 2 + 1], s);
    }
}

// Kernel 3: mean over batch of masked/total ratios.
__global__ void k_final(const float* __restrict__ acc,
                        float* __restrict__ out) {
    int t = threadIdx.x;  // 64 threads
    float r = 0.0f;
    if (t < 32) r = acc[t * 2 + 0] / acc[t * 2 + 1];
#pragma unroll
    for (int off = 32; off > 0; off >>= 1) r += __shfl_down(r, off);
    if (t == 0) out[0] = r * (1.0f / 32.0f);
}

extern "C" void kernel_launch(void* const* d_in, const int* in_sizes, int n_in,
                              void* d_out, int out_size, void* d_ws,
                              size_t ws_size, hipStream_t stream) {
    const float* img = (const float*)d_in[0];
    float* out = (float*)d_out;

    float2* buf = (float2*)d_ws;
    const size_t buf_bytes = (size_t)32 * N * N * sizeof(float2);  // 67 MB
    float* acc = (float*)((char*)d_ws + buf_bytes);

    hipMemsetAsync(acc, 0, 64 * sizeof(float), stream);

    dim3 grid(N, 32);
    k_gray_rowfft<<<grid, 256, 0, stream>>>(img, buf);
    k_colfft_reduce<<<grid, 256, 0, stream>>>(buf, acc);
    k_final<<<1, 64, 0, stream>>>(acc, out);
}

// Round 2
// 294.225 us; speedup vs baseline: 1.6480x; 1.6480x over previous
//
#include <hip/hip_runtime.h>
#include <math.h>

#define N 512
#define LOGN 9
// LDS anti-bank-conflict padding: insert one slot every 32 floats.
#define NPAD(i) ((i) + ((i) >> 5))
#define FSZ 528            // NPAD(511)=526 < 528, array size per FFT
#define NCOL 257           // Hermitian: columns v = 0..256 only

// mask: (u-256)^2 + (v-256)^2 <= (51.2)^2. Integer dist^2 exact in fp32.
#define RAD2 2621.44f

// ---------------------------------------------------------------------------
// In-LDS 512-point radix-2 DIT FFT, executed by ONE wave (64 lanes), 4
// butterflies per lane per stage. Data wave-private -> no __syncthreads.
// Twiddles: tw[k] = (cos, sin) of +2*pi*k/N; butterfly multiplies by (c - i*s).
// ---------------------------------------------------------------------------
__device__ __forceinline__ void fft512_wave(float* sr, float* si,
                                            const float* twr, const float* twi,
                                            int l) {
#pragma unroll
    for (int s = 1; s <= LOGN; ++s) {
        int half = 1 << (s - 1);
#pragma unroll
        for (int j = 0; j < 4; ++j) {
            int bf  = l + 64 * j;              // butterfly 0..255
            int pos = bf & (half - 1);
            int i1  = ((bf >> (s - 1)) << s) + pos;
            int i2  = i1 + half;
            int tix = pos << (LOGN - s);
            float c  = twr[NPAD(tix)];
            float sn = twi[NPAD(tix)];
            float xr = sr[NPAD(i2)], xi = si[NPAD(i2)];
            float tr = c * xr + sn * xi;       // (c - i*sn)*(xr + i*xi)
            float ti = c * xi - sn * xr;
            float ur = sr[NPAD(i1)], ui = si[NPAD(i1)];
            sr[NPAD(i2)] = ur - tr; si[NPAD(i2)] = ui - ti;
            sr[NPAD(i1)] = ur + tr; si[NPAD(i1)] = ui + ti;
        }
        __builtin_amdgcn_wave_barrier();       // keep stages ordered in sched
    }
}

// ---------------------------------------------------------------------------
// K1: grayscale + row FFTs (2 real rows packed per complex FFT) + Hermitian
// unpack + transposed write. Block = 512 threads = 8 waves = 16 image rows.
// Output: buf[b][v][h], v=0..256 (float2), h-contiguous.
// ---------------------------------------------------------------------------
__global__ __launch_bounds__(512) void k_gray_rowfft(
    const float* __restrict__ img, float2* __restrict__ buf) {
    __shared__ float zr[8][FSZ], zi[8][FSZ];
    __shared__ float twr[264], twi[264];       // NPAD(255)=262 < 264

    const int t  = threadIdx.x;
    const int wv = t >> 6;
    const int l  = t & 63;
    const int b    = blockIdx.y;
    const int tile = blockIdx.x;               // rows tile*16 .. tile*16+15

    if (t < 256) {
        float ang = (float)(2.0 * M_PI / (double)N) * (float)t;
        twr[NPAD(t)] = cosf(ang);
        twi[NPAD(t)] = sinf(ang);
    }

    const size_t plane = (size_t)N * N;
    const float* base = img + (size_t)b * 3 * plane;
    const int he = tile * 16 + 2 * wv;         // even row of this wave's pair
    const float* re0 = base + (size_t)he * N;
    const float* ro0 = re0 + N;                // odd row

    // z[w] = gray_even(w) + i*gray_odd(w), stored bit-reversed (wave-private)
#pragma unroll
    for (int j = 0; j < 8; ++j) {
        int w = l + 64 * j;
        float ge = (re0[w] + re0[plane + w] + re0[2 * plane + w]) * (1.0f / 3.0f);
        float go = (ro0[w] + ro0[plane + w] + ro0[2 * plane + w]) * (1.0f / 3.0f);
        int r = __brev((unsigned)w) >> (32 - LOGN);
        zr[wv][NPAD(r)] = ge;
        zi[wv][NPAD(r)] = go;
    }
    __syncthreads();                           // covers twiddle table init

    fft512_wave(zr[wv], zi[wv], twr, twi, l);
    __syncthreads();                           // write phase reads all waves

    // Unpack F_even/F_odd from packed spectrum and write transposed:
    // element (v, h): h local 0..15, pair p = h>>1, parity = h&1.
    const int h    = t & 15;
    const int p    = h >> 1;
    const int odd  = h & 1;
    const int slot = t >> 4;                   // 0..31
    float2* ob = buf + (size_t)b * NCOL * N;
#pragma unroll
    for (int it = 0; it <= 8; ++it) {
        int v = slot + 32 * it;
        if (v < NCOL) {
            int vn = (N - v) & (N - 1);
            float Zr  = zr[p][NPAD(v)],  Zi  = zi[p][NPAD(v)];
            float Zr2 = zr[p][NPAD(vn)], Zi2 = zi[p][NPAD(vn)];
            float Fr, Fi;
            if (!odd) { Fr = 0.5f * (Zr + Zr2); Fi = 0.5f * (Zi - Zi2); }
            else      { Fr = 0.5f * (Zi + Zi2); Fi = 0.5f * (Zr2 - Zr); }
            ob[(size_t)v * N + tile * 16 + h] = make_float2(Fr, Fi);
        }
    }
}

// ---------------------------------------------------------------------------
// K2: column FFTs (reading contiguous transposed rows) + masked/total
// magnitude reduction with Hermitian column weights. Block = 512 thr = 8 cols.
// ---------------------------------------------------------------------------
__global__ __launch_bounds__(512) void k_colfft_reduce(
    const float2* __restrict__ buf, float* __restrict__ acc) {
    __shared__ float zr[8][FSZ], zi[8][FSZ];
    __shared__ float twr[264], twi[264];

    const int t  = threadIdx.x;
    const int wv = t >> 6;
    const int l  = t & 63;
    const int b  = blockIdx.y;
    const int v  = blockIdx.x * 8 + wv;        // 0..263 (257..263 dummies)
    const int vv = v > 256 ? 256 : v;

    if (t < 256) {
        float ang = (float)(2.0 * M_PI / (double)N) * (float)t;
        twr[NPAD(t)] = cosf(ang);
        twi[NPAD(t)] = sinf(ang);
    }

    const float2* col = buf + ((size_t)b * NCOL + vv) * N;
#pragma unroll
    for (int j = 0; j < 8; ++j) {
        int u = l + 64 * j;
        float2 zv = col[u];
        int r = __brev((unsigned)u) >> (32 - LOGN);
        zr[wv][NPAD(r)] = zv.x;
        zi[wv][NPAD(r)] = zv.y;
    }
    __syncthreads();                           // twiddle table visibility

    fft512_wave(zr[wv], zi[wv], twr, twi, l);
    // No barrier: this wave reads only its own FFT result below.

    // weight: v==0 or v==256 -> 1; 1..255 -> 2 (Hermitian mirror); dummy -> 0
    float wcol = (v == 0 || v == 256) ? 1.0f : (v < 256 ? 2.0f : 0.0f);
    float dx  = (float)(vv - 256);
    float dx2 = dx * dx;
    float msum = 0.0f, tsum = 0.0f;
#pragma unroll
    for (int j = 0; j < 8; ++j) {
        int u = l + 64 * j;
        float re = zr[wv][NPAD(u)], im = zi[wv][NPAD(u)];
        float mag = sqrtf(re * re + im * im);
        tsum += mag;
        float dy = (float)(u - 256);
        if (dy * dy + dx2 <= RAD2) msum += mag;
    }
    msum *= wcol; tsum *= wcol;
#pragma unroll
    for (int off = 32; off > 0; off >>= 1) {
        msum += __shfl_down(msum, off);
        tsum += __shfl_down(tsum, off);
    }
    if (l == 0) {
        atomicAdd(&acc[b * 2 + 0], msum);
        atomicAdd(&acc[b * 2 + 1], tsum);
    }
}

// K3: mean over batch of masked/total ratios.
__global__ void k_final(const float* __restrict__ acc,
                        float* __restrict__ out) {
    int t = threadIdx.x;                       // 64 threads
    float r = 0.0f;
    if (t < 32) r = acc[t * 2 + 0] / acc[t * 2 + 1];
#pragma unroll
    for (int off = 32; off > 0; off >>= 1) r += __shfl_down(r, off);
    if (t == 0) out[0] = r * (1.0f / 32.0f);
}

extern "C" void kernel_launch(void* const* d_in, const int* in_sizes, int n_in,
                              void* d_out, int out_size, void* d_ws,
                              size_t ws_size, hipStream_t stream) {
    const float* img = (const float*)d_in[0];
    float* out = (float*)d_out;

    float2* buf = (float2*)d_ws;               // [32][257][512] float2 ~ 33.7MB
    const size_t buf_bytes = (size_t)32 * NCOL * N * sizeof(float2);
    float* acc = (float*)((char*)d_ws + buf_bytes);

    hipMemsetAsync(acc, 0, 64 * sizeof(float), stream);

    dim3 g1(N / 16, 32);                       // 32 row-tiles x 32 images
    k_gray_rowfft<<<g1, 512, 0, stream>>>(img, buf);

    dim3 g2((NCOL + 7) / 8, 32);               // 33 col-groups x 32 images
    k_colfft_reduce<<<g2, 512, 0, stream>>>(buf, acc);

    k_final<<<1, 64, 0, stream>>>(acc, out);
}

// Round 3
// 186.779 us; speedup vs baseline: 2.5961x; 1.5753x over previous
//
#include <hip/hip_runtime.h>
#include <math.h>

#define N 512
#define LOGN 9
#define NPAD(i) ((i) + ((i) >> 5))
#define FSZ 528
#define NCOL 257
// mask: (u-256)^2 + (v-256)^2 <= 51.2^2 (integer dist^2 exact in fp32)
#define RAD2 2621.44f
#define SQ2H 0.70710678f

// ---------------------------------------------------------------------------
// In-register 8-point DFT (natural order in/out), complex in (xr, xi).
// ---------------------------------------------------------------------------
__device__ __forceinline__ void dft8(float (&xr)[8], float (&xi)[8]) {
    float e0r = xr[0] + xr[4], e0i = xi[0] + xi[4];
    float e1r = xr[0] - xr[4], e1i = xi[0] - xi[4];
    float e2r = xr[2] + xr[6], e2i = xi[2] + xi[6];
    float e3r = xr[2] - xr[6], e3i = xi[2] - xi[6];
    float E0r = e0r + e2r, E0i = e0i + e2i;
    float E2r = e0r - e2r, E2i = e0i - e2i;
    float E1r = e1r + e3i, E1i = e1i - e3r;   // e1 - i*e3
    float E3r = e1r - e3i, E3i = e1i + e3r;   // e1 + i*e3
    float o0r = xr[1] + xr[5], o0i = xi[1] + xi[5];
    float o1r = xr[1] - xr[5], o1i = xi[1] - xi[5];
    float o2r = xr[3] + xr[7], o2i = xi[3] + xi[7];
    float o3r = xr[3] - xr[7], o3i = xi[3] - xi[7];
    float O0r = o0r + o2r, O0i = o0i + o2i;
    float O2r = o0r - o2r, O2i = o0i - o2i;
    float O1r = o1r + o3i, O1i = o1i - o3r;
    float O3r = o1r - o3i, O3i = o1i + o3r;
    // O1 *= W8^1 = s(1-i); O2 *= -i; O3 *= W8^3 = s(-1-i)
    float t1r = SQ2H * (O1r + O1i), t1i = SQ2H * (O1i - O1r);
    float t2r = O2i,                t2i = -O2r;
    float t3r = SQ2H * (O3i - O3r), t3i = -SQ2H * (O3r + O3i);
    xr[0] = E0r + O0r; xi[0] = E0i + O0i;
    xr[4] = E0r - O0r; xi[4] = E0i - O0i;
    xr[1] = E1r + t1r; xi[1] = E1i + t1i;
    xr[5] = E1r - t1r; xi[5] = E1i - t1i;
    xr[2] = E2r + t2r; xi[2] = E2i + t2i;
    xr[6] = E2r - t2r; xi[6] = E2i - t2i;
    xr[3] = E3r + t3r; xi[3] = E3i + t3i;
    xr[7] = E3r - t3r; xi[7] = E3i - t3i;
}

// ---------------------------------------------------------------------------
// Wave-level 512-pt FFT, all in registers. 512 = 8 (in-lane) x 64 (cross-lane).
// In:  lane l, reg j holds x[64*j + l].
// Out: lane l, reg k holds X[8*br6(l) + k], br6 = 6-bit reversal.
// Cross-lane part: radix-2 DIF over lanes via __shfl_xor (no LDS).
// ---------------------------------------------------------------------------
__device__ __forceinline__ void fft512_regs(float (&zr)[8], float (&zi)[8],
                                            int l) {
    dft8(zr, zi);
    // twiddle z[k] *= e^{-2*pi*i * l * k / 512}
    float a = (-2.0f * (float)M_PI / 512.0f) * (float)l;
    float w1r, w1i;
    __sincosf(a, &w1i, &w1r);
    float wr = w1r, wi = w1i;
#pragma unroll
    for (int k = 1; k < 8; ++k) {
        float tr = zr[k] * wr - zi[k] * wi;
        float ti = zr[k] * wi + zi[k] * wr;
        zr[k] = tr; zi[k] = ti;
        float nr = wr * w1r - wi * w1i;
        float ni = wr * w1i + wi * w1r;
        wr = nr; wi = ni;
    }
    // 64-pt DIF across lanes: A' = a + b ; B' = (a - b) * W_m^j
#pragma unroll
    for (int half = 32; half >= 1; half >>= 1) {
        int j = l & (half - 1);
        float ang = (-(float)M_PI / (float)half) * (float)j;
        float swr, swi;
        __sincosf(ang, &swi, &swr);
        bool up = (l & half) != 0;
        float sgn = up ? -1.0f : 1.0f;
        float wsr = up ? swr : 1.0f;
        float wsi = up ? swi : 0.0f;
#pragma unroll
        for (int k = 0; k < 8; ++k) {
            float pr = __shfl_xor(zr[k], half);
            float pi = __shfl_xor(zi[k], half);
            float tr = fmaf(sgn, zr[k], pr);
            float ti = fmaf(sgn, zi[k], pi);
            zr[k] = tr * wsr - ti * wsi;
            zi[k] = tr * wsi + ti * wsr;
        }
    }
}

// ---------------------------------------------------------------------------
// K1: grayscale + packed row-pair FFT (regs) + Hermitian unpack + transposed
// write. 512 thr = 8 waves = 16 rows. Output buf[b][v][h], v=0..256.
// ---------------------------------------------------------------------------
__global__ __launch_bounds__(512) void k_gray_rowfft(
    const float* __restrict__ img, float2* __restrict__ buf) {
    __shared__ float sr[8][FSZ], si[8][FSZ];
    const int t = threadIdx.x, wv = t >> 6, l = t & 63;
    const int b = blockIdx.y, tile = blockIdx.x;
    const size_t plane = (size_t)N * N;
    const float* base = img + (size_t)b * 3 * plane;
    const int he = tile * 16 + 2 * wv;
    const float* p0 = base + (size_t)he * N;
    const float* p1 = p0 + N;

    float zr[8], zi[8];
#pragma unroll
    for (int j = 0; j < 8; ++j) {
        int w = l + 64 * j;
        zr[j] = (p0[w] + p0[plane + w] + p0[2 * plane + w]) * (1.0f / 3.0f);
        zi[j] = (p1[w] + p1[plane + w] + p1[2 * plane + w]) * (1.0f / 3.0f);
    }

    fft512_regs(zr, zi, l);

    const int rb = __brev((unsigned)l) >> 26;
#pragma unroll
    for (int k = 0; k < 8; ++k) {
        int u = 8 * rb + k;
        sr[wv][NPAD(u)] = zr[k];
        si[wv][NPAD(u)] = zi[k];
    }
    __syncthreads();

    // unpack F_even/F_odd (validated epilogue): element (v, h)
    const int h = t & 15, p = h >> 1, odd = h & 1, slot = t >> 4;
    float2* ob = buf + (size_t)b * NCOL * N;
#pragma unroll
    for (int it = 0; it <= 8; ++it) {
        int v = slot + 32 * it;
        if (v < NCOL) {
            int vn = (N - v) & (N - 1);
            float Zr  = sr[p][NPAD(v)],  Zi  = si[p][NPAD(v)];
            float Zr2 = sr[p][NPAD(vn)], Zi2 = si[p][NPAD(vn)];
            float Fr, Fi;
            if (!odd) { Fr = 0.5f * (Zr + Zr2); Fi = 0.5f * (Zi - Zi2); }
            else      { Fr = 0.5f * (Zi + Zi2); Fi = 0.5f * (Zr2 - Zr); }
            ob[(size_t)v * N + tile * 16 + h] = make_float2(Fr, Fi);
        }
    }
}

// ---------------------------------------------------------------------------
// K2: column FFT fully in registers (zero LDS on the datapath) + masked/total
// reduction with Hermitian weights. 256 thr = 4 waves = 4 columns.
// ---------------------------------------------------------------------------
__global__ __launch_bounds__(256) void k_colfft_reduce(
    const float2* __restrict__ buf, float* __restrict__ acc) {
    __shared__ float red[8];
    const int t = threadIdx.x, wv = t >> 6, l = t & 63;
    const int b = blockIdx.y;
    const int v = blockIdx.x * 4 + wv;         // 0..259 (257.. dummies)
    const int vv = v > 256 ? 256 : v;

    const float2* col = buf + ((size_t)b * NCOL + vv) * N;
    float zr[8], zi[8];
#pragma unroll
    for (int j = 0; j < 8; ++j) {
        float2 z = col[64 * j + l];
        zr[j] = z.x; zi[j] = z.y;
    }

    fft512_regs(zr, zi, l);

    const float wcol = (v == 0 || v == 256) ? 1.0f : (v < 256 ? 2.0f : 0.0f);
    const float dx = (float)(vv - 256);
    const float dx2 = dx * dx;
    const int rb = __brev((unsigned)l) >> 26;
    float msum = 0.0f, tsum = 0.0f;
#pragma unroll
    for (int k = 0; k < 8; ++k) {
        int u = 8 * rb + k;
        float mag = sqrtf(zr[k] * zr[k] + zi[k] * zi[k]);
        tsum += mag;
        float dy = (float)(u - 256);
        if (dy * dy + dx2 <= RAD2) msum += mag;
    }
    msum *= wcol; tsum *= wcol;
#pragma unroll
    for (int off = 32; off > 0; off >>= 1) {
        msum += __shfl_down(msum, off);
        tsum += __shfl_down(tsum, off);
    }
    if (l == 0) { red[wv * 2] = msum; red[wv * 2 + 1] = tsum; }
    __syncthreads();
    if (t == 0) {
        atomicAdd(&acc[b * 2 + 0], red[0] + red[2] + red[4] + red[6]);
        atomicAdd(&acc[b * 2 + 1], red[1] + red[3] + red[5] + red[7]);
    }
}

// K3: mean over batch of ratios.
__global__ void k_final(const float* __restrict__ acc,
                        float* __restrict__ out) {
    int t = threadIdx.x;                       // 64 threads
    float r = 0.0f;
    if (t < 32) r = acc[t * 2 + 0] / acc[t * 2 + 1];
#pragma unroll
    for (int off = 32; off > 0; off >>= 1) r += __shfl_down(r, off);
    if (t == 0) out[0] = r * (1.0f / 32.0f);
}

extern "C" void kernel_launch(void* const* d_in, const int* in_sizes, int n_in,
                              void* d_out, int out_size, void* d_ws,
                              size_t ws_size, hipStream_t stream) {
    const float* img = (const float*)d_in[0];
    float* out = (float*)d_out;

    float2* buf = (float2*)d_ws;               // [32][257][512] float2 ~ 33.7MB
    const size_t buf_bytes = (size_t)32 * NCOL * N * sizeof(float2);
    float* acc = (float*)((char*)d_ws + buf_bytes);

    hipMemsetAsync(acc, 0, 64 * sizeof(float), stream);

    dim3 g1(N / 16, 32);                       // 32 row-tiles x 32 images
    k_gray_rowfft<<<g1, 512, 0, stream>>>(img, buf);

    dim3 g2((NCOL + 3) / 4, 32);               // 65 col-groups x 32 images
    k_colfft_reduce<<<g2, 256, 0, stream>>>(buf, acc);

    k_final<<<1, 64, 0, stream>>>(acc, out);
}

// Round 4
// 185.728 us; speedup vs baseline: 2.6108x; 1.0057x over previous
//
#include <hip/hip_runtime.h>
#include <math.h>

#define N 512
#define NPAD(i) ((i) + ((i) >> 5))
#define FSZ 532            // NPAD(511)=526 < 532; 532%32=20 -> 8 slabs spread banks
#define NCOL 257           // Hermitian: columns v = 0..256 only
// mask: (u-256)^2 + (v-256)^2 <= 51.2^2 (integer dist^2 exact in fp32)
#define RAD2 2621.44f
#define SQ2H 0.70710678f

// ---------------------------------------------------------------------------
// In-register 8-point DFT, natural order in (time) / natural order out (freq).
// ---------------------------------------------------------------------------
__device__ __forceinline__ void dft8(float (&xr)[8], float (&xi)[8]) {
    float e0r = xr[0] + xr[4], e0i = xi[0] + xi[4];
    float e1r = xr[0] - xr[4], e1i = xi[0] - xi[4];
    float e2r = xr[2] + xr[6], e2i = xi[2] + xi[6];
    float e3r = xr[2] - xr[6], e3i = xi[2] - xi[6];
    float E0r = e0r + e2r, E0i = e0i + e2i;
    float E2r = e0r - e2r, E2i = e0i - e2i;
    float E1r = e1r + e3i, E1i = e1i - e3r;   // e1 - i*e3
    float E3r = e1r - e3i, E3i = e1i + e3r;   // e1 + i*e3
    float o0r = xr[1] + xr[5], o0i = xi[1] + xi[5];
    float o1r = xr[1] - xr[5], o1i = xi[1] - xi[5];
    float o2r = xr[3] + xr[7], o2i = xi[3] + xi[7];
    float o3r = xr[3] - xr[7], o3i = xi[3] - xi[7];
    float O0r = o0r + o2r, O0i = o0i + o2i;
    float O2r = o0r - o2r, O2i = o0i - o2i;
    float O1r = o1r + o3i, O1i = o1i - o3r;
    float O3r = o1r - o3i, O3i = o1i + o3r;
    float t1r = SQ2H * (O1r + O1i), t1i = SQ2H * (O1i - O1r);
    float t2r = O2i,                t2i = -O2r;
    float t3r = SQ2H * (O3i - O3r), t3i = -SQ2H * (O3r + O3i);
    xr[0] = E0r + O0r; xi[0] = E0i + O0i;
    xr[4] = E0r - O0r; xi[4] = E0i - O0i;
    xr[1] = E1r + t1r; xi[1] = E1i + t1i;
    xr[5] = E1r - t1r; xi[5] = E1i - t1i;
    xr[2] = E2r + t2r; xi[2] = E2i + t2i;
    xr[6] = E2r - t2r; xi[6] = E2i - t2i;
    xr[3] = E3r + t3r; xi[3] = E3i + t3i;
    xr[7] = E3r - t3r; xi[7] = E3i - t3i;
}

// ---------------------------------------------------------------------------
// Wave-level 512-pt FFT. NEW layout: lane l, reg k holds x[8*l + k] (input
// contiguous per lane -> float4 global loads). 512 = 64(cross-lane) x 8(in).
//   X[w + 64*t] = DFT8_k( W512^{k*w} * Y_k[w] ),  w = br6(l) after DIF.
// Out: lane l, reg t holds X[br6(l) + 64*t].
// Twiddles via v_sin/v_cos in REVOLUTIONS (all angles exact rationals).
// ---------------------------------------------------------------------------
__device__ __forceinline__ void fft512_regs(float (&zr)[8], float (&zi)[8],
                                            int l) {
    // 64-pt radix-2 DIF across lanes, applied to each reg k independently.
#pragma unroll
    for (int half = 32; half >= 1; half >>= 1) {
        const int j = l & (half - 1);
        const float f = (float)j * (0.5f / (float)half);   // revolutions
        const float c = __builtin_amdgcn_cosf(f);          // cos(2*pi*f)
        const float s = __builtin_amdgcn_sinf(f);          // sin(2*pi*f)
        const bool up = (l & half) != 0;
        const float sgn = up ? -1.0f : 1.0f;
        const float wc  = up ? c : 1.0f;                   // W = wc - i*ws
        const float ws  = up ? s : 0.0f;
#pragma unroll
        for (int k = 0; k < 8; ++k) {
            float pr = __shfl_xor(zr[k], half);
            float pi = __shfl_xor(zi[k], half);
            float tr = fmaf(sgn, zr[k], pr);
            float ti = fmaf(sgn, zi[k], pi);
            zr[k] = tr * wc + ti * ws;
            zi[k] = ti * wc - tr * ws;
        }
    }
    // twiddle reg k by W512^{k*w}, w = br6(l)
    const int w = __brev((unsigned)l) >> 26;
#pragma unroll
    for (int k = 1; k < 8; ++k) {
        const float f = (float)(k * w) * (1.0f / 512.0f);  // exact rational
        const float c = __builtin_amdgcn_cosf(f);
        const float s = __builtin_amdgcn_sinf(f);
        float tr = zr[k] * c + zi[k] * s;                  // * (c - i*s)
        float ti = zi[k] * c - zr[k] * s;
        zr[k] = tr; zi[k] = ti;
    }
    dft8(zr, zi);
}

// ---------------------------------------------------------------------------
// K1: grayscale + packed row-pair FFT + Hermitian unpack + transposed write.
// 512 thr = 8 waves = 16 rows. Output buf[b][v][h], v=0..256, h-contiguous.
// ---------------------------------------------------------------------------
__global__ __launch_bounds__(512) void k_gray_rowfft(
    const float* __restrict__ img, float2* __restrict__ buf) {
    __shared__ float sr[8][FSZ], si[8][FSZ];
    const int t = threadIdx.x, wv = t >> 6, l = t & 63;
    const int b = blockIdx.y, tile = blockIdx.x;
    const size_t plane = (size_t)N * N;
    const float* base = img + (size_t)b * 3 * plane;
    const int he = tile * 16 + 2 * wv;
    const float* p0 = base + (size_t)he * N;
    const float* p1 = p0 + N;

    // vectorized grayscale: lane l owns pixels 8l..8l+7 of both rows
    const float4* c0e = (const float4*)(p0);
    const float4* c1e = (const float4*)(p0 + plane);
    const float4* c2e = (const float4*)(p0 + 2 * plane);
    const float4* c0o = (const float4*)(p1);
    const float4* c1o = (const float4*)(p1 + plane);
    const float4* c2o = (const float4*)(p1 + 2 * plane);

    float zr[8], zi[8];
    const float inv3 = 1.0f / 3.0f;
#pragma unroll
    for (int q = 0; q < 2; ++q) {
        int idx = 2 * l + q;
        float4 a = c0e[idx], bb = c1e[idx], c = c2e[idx];
        float4 d = c0o[idx], e = c1o[idx], g = c2o[idx];
        zr[4 * q + 0] = (a.x + bb.x + c.x) * inv3;
        zr[4 * q + 1] = (a.y + bb.y + c.y) * inv3;
        zr[4 * q + 2] = (a.z + bb.z + c.z) * inv3;
        zr[4 * q + 3] = (a.w + bb.w + c.w) * inv3;
        zi[4 * q + 0] = (d.x + e.x + g.x) * inv3;
        zi[4 * q + 1] = (d.y + e.y + g.y) * inv3;
        zi[4 * q + 2] = (d.z + e.z + g.z) * inv3;
        zi[4 * q + 3] = (d.w + e.w + g.w) * inv3;
    }

    fft512_regs(zr, zi, l);

    // park packed spectrum Z[v] in LDS at natural index v = br6(l) + 64*t
    const int w = __brev((unsigned)l) >> 26;
#pragma unroll
    for (int k = 0; k < 8; ++k) {
        int u = w + 64 * k;
        sr[wv][NPAD(u)] = zr[k];
        si[wv][NPAD(u)] = zi[k];
    }
    __syncthreads();

    // unpack F_even/F_odd; each lane emits BOTH parities of pair p = t&7
    // as one float4 (columns h2, h2+1 of the tile) for 5 v-slices.
    const int p = t & 7;
    const int h2 = 2 * p;
    const int slot = t >> 3;                   // 0..63
    float2* ob = buf + (size_t)b * NCOL * N;
#pragma unroll
    for (int it = 0; it < 5; ++it) {
        int v = slot + 64 * it;
        if (v < NCOL) {
            int vn = (N - v) & (N - 1);
            float Zr  = sr[p][NPAD(v)],  Zi  = si[p][NPAD(v)];
            float Zr2 = sr[p][NPAD(vn)], Zi2 = si[p][NPAD(vn)];
            float4 o;
            o.x = 0.5f * (Zr + Zr2);           // F_even.re
            o.y = 0.5f * (Zi - Zi2);           // F_even.im
            o.z = 0.5f * (Zi + Zi2);           // F_odd.re
            o.w = 0.5f * (Zr2 - Zr);           // F_odd.im
            *(float4*)(&ob[(size_t)v * N + tile * 16 + h2]) = o;
        }
    }
}

// ---------------------------------------------------------------------------
// K2: column FFT fully in registers + masked/total reduction with Hermitian
// weights. 256 thr = 4 waves = 4 columns; float4 loads (2 complex each).
// ---------------------------------------------------------------------------
__global__ __launch_bounds__(256) void k_colfft_reduce(
    const float2* __restrict__ buf, float* __restrict__ acc) {
    __shared__ float red[8];
    const int t = threadIdx.x, wv = t >> 6, l = t & 63;
    const int b = blockIdx.y;
    const int v = blockIdx.x * 4 + wv;         // 0..259 (257.. dummies)
    const int vv = v > 256 ? 256 : v;

    const float4* col = (const float4*)(buf + ((size_t)b * NCOL + vv) * N);
    float zr[8], zi[8];
#pragma unroll
    for (int q = 0; q < 4; ++q) {
        float4 z = col[4 * l + q];             // complex 8l+2q, 8l+2q+1
        zr[2 * q]     = z.x; zi[2 * q]     = z.y;
        zr[2 * q + 1] = z.z; zi[2 * q + 1] = z.w;
    }

    fft512_regs(zr, zi, l);

    const float wcol = (v == 0 || v == 256) ? 1.0f : (v < 256 ? 2.0f : 0.0f);
    const float dx = (float)(vv - 256);
    const float dx2 = dx * dx;
    const int w = __brev((unsigned)l) >> 26;
    float msum = 0.0f, tsum = 0.0f;
#pragma unroll
    for (int k = 0; k < 8; ++k) {
        int u = w + 64 * k;
        float mag = sqrtf(zr[k] * zr[k] + zi[k] * zi[k]);
        tsum += mag;
        float dy = (float)(u - 256);
        if (dy * dy + dx2 <= RAD2) msum += mag;
    }
    msum *= wcol; tsum *= wcol;
#pragma unroll
    for (int off = 32; off > 0; off >>= 1) {
        msum += __shfl_down(msum, off);
        tsum += __shfl_down(tsum, off);
    }
    if (l == 0) { red[wv * 2] = msum; red[wv * 2 + 1] = tsum; }
    __syncthreads();
    if (t == 0) {
        atomicAdd(&acc[b * 2 + 0], red[0] + red[2] + red[4] + red[6]);
        atomicAdd(&acc[b * 2 + 1], red[1] + red[3] + red[5] + red[7]);
    }
}

// K3: mean over batch of ratios.
__global__ void k_final(const float* __restrict__ acc,
                        float* __restrict__ out) {
    int t = threadIdx.x;                       // 64 threads
    float r = 0.0f;
    if (t < 32) r = acc[t * 2 + 0] / acc[t * 2 + 1];
#pragma unroll
    for (int off = 32; off > 0; off >>= 1) r += __shfl_down(r, off);
    if (t == 0) out[0] = r * (1.0f / 32.0f);
}

extern "C" void kernel_launch(void* const* d_in, const int* in_sizes, int n_in,
                              void* d_out, int out_size, void* d_ws,
                              size_t ws_size, hipStream_t stream) {
    const float* img = (const float*)d_in[0];
    float* out = (float*)d_out;

    float2* buf = (float2*)d_ws;               // [32][257][512] float2 ~ 33.7MB
    const size_t buf_bytes = (size_t)32 * NCOL * N * sizeof(float2);
    float* acc = (float*)((char*)d_ws + buf_bytes);

    hipMemsetAsync(acc, 0, 64 * sizeof(float), stream);

    dim3 g1(N / 16, 32);                       // 32 row-tiles x 32 images
    k_gray_rowfft<<<g1, 512, 0, stream>>>(img, buf);

    dim3 g2((NCOL + 3) / 4, 32);               // 65 col-groups x 32 images
    k_colfft_reduce<<<g2, 256, 0, stream>>>(buf, acc);

    k_final<<<1, 64, 0, stream>>>(acc, out);
}